// Round 20
// baseline (1256.610 us; speedup 1.0000x reference)
//
#include <hip/hip_runtime.h>
#include <math.h>

#define NN 16384
#define NE 262144

// ---------------- workspace layout (units: 4 bytes) ----------------
constexpr size_t OFF_PART  = 0;                               // 192 (also scan bsum)
constexpr size_t OFF_MEAN  = 256;                             // 3
constexpr size_t OFF_T     = 512;                             // 16*64
constexpr size_t OFF_BIAS  = 1536;                            // 64
constexpr size_t OFF_S     = 2048;                            // NN*64
constexpr size_t OFF_V     = OFF_S     + (size_t)NN * 64;     // NN*192
constexpr size_t OFF_GEOM  = OFF_V     + (size_t)NN * 192;    // NE*4 (float4, edge order)
constexpr size_t OFF_GEOMC = OFF_GEOM  + (size_t)NE * 4;      // NE*4 (float4, CSR order)
constexpr size_t OFF_QS    = OFF_GEOMC + (size_t)NE * 4;      // NN*64
constexpr size_t OFF_KS    = OFF_QS    + (size_t)NN * 64;     // NN*64
constexpr size_t OFF_QV    = OFF_KS    + (size_t)NN * 64;     // NN*192
constexpr size_t OFF_KV    = OFF_QV    + (size_t)NN * 192;    // NN*192
constexpr size_t OFF_RAD   = OFF_KV    + (size_t)NN * 192;    // NE*64 (CSR order)
constexpr size_t OFF_INT   = OFF_RAD   + (size_t)NE * 64;
constexpr size_t I_ROWPTR  = OFF_INT;                         // NN+1
constexpr size_t I_CURSOR  = OFF_INT + 16640;                 // NN
constexpr size_t I_SRCC    = I_CURSOR + (size_t)NN;           // NE (CSR order)
// total ~= 31.8M * 4B ~= 127 MB

static __device__ __forceinline__ double sigmoidd_(double x) {
  return 1.0 / (1.0 + exp(-x));
}

// fast e^x for x <= 0 (softmax path). Rel err ~2e-13. fast_exp(0) == 1.0 exactly.
static __device__ __forceinline__ double fast_exp(double x) {
  x = fmax(x, -708.0);                       // also maps -inf -> tiny finite
  double y = x * 1.4426950408889634074;      // x * log2(e)
  double k = rint(y);
  double r = fma(k, -6.93147180369123816490e-01, x);
  r = fma(k, -1.90821492927058770002e-10, r);  // r = x - k*ln2, |r| <= 0.3466
  double p = 2.755731922398589e-7;             // 1/10!
  p = fma(p, r, 2.7557319223985893e-6);        // 1/9!
  p = fma(p, r, 2.48015873015873016e-5);       // 1/8!
  p = fma(p, r, 1.98412698412698413e-4);       // 1/7!
  p = fma(p, r, 1.38888888888888889e-3);       // 1/6!
  p = fma(p, r, 8.33333333333333333e-3);       // 1/5!
  p = fma(p, r, 4.16666666666666667e-2);       // 1/4!
  p = fma(p, r, 1.66666666666666667e-1);       // 1/3!
  p = fma(p, r, 0.5);
  p = fma(p, r, 1.0);
  p = fma(p, r, 1.0);
  long long ki = (long long)k;                 // k in [-1021, 0]
  double sc = __longlong_as_double((unsigned long long)(1023LL + ki) << 52);
  return p * sc;
}

// ---------------- mean of coordinates ----------------
__global__ void k_mean_partial(const float* __restrict__ coords, float* __restrict__ partials) {
  __shared__ double sm[3][256];
  int tid = threadIdx.x;
  int n = blockIdx.x * 256 + tid;
  sm[0][tid] = (double)coords[n * 3 + 0];
  sm[1][tid] = (double)coords[n * 3 + 1];
  sm[2][tid] = (double)coords[n * 3 + 2];
  __syncthreads();
  for (int off = 128; off > 0; off >>= 1) {
    if (tid < off) {
      sm[0][tid] += sm[0][tid + off];
      sm[1][tid] += sm[1][tid + off];
      sm[2][tid] += sm[2][tid + off];
    }
    __syncthreads();
  }
  if (tid == 0) {
    partials[blockIdx.x * 3 + 0] = (float)sm[0][0];
    partials[blockIdx.x * 3 + 1] = (float)sm[1][0];
    partials[blockIdx.x * 3 + 2] = (float)sm[2][0];
  }
}

__global__ void k_mean_final(const float* __restrict__ partials, float* __restrict__ mean) {
  int lane = threadIdx.x;
  double s0 = (double)partials[lane * 3 + 0];
  double s1 = (double)partials[lane * 3 + 1];
  double s2 = (double)partials[lane * 3 + 2];
  for (int off = 32; off > 0; off >>= 1) {
    s0 += __shfl_xor(s0, off);
    s1 += __shfl_xor(s1, off);
    s2 += __shfl_xor(s2, off);
  }
  if (lane == 0) {
    mean[0] = (float)(s0 * (1.0 / (double)NN));
    mean[1] = (float)(s1 * (1.0 / (double)NN));
    mean[2] = (float)(s2 * (1.0 / (double)NN));
  }
}

// ---------------- s-embedding table: T[a][f] and time bias ----------------
__global__ void k_prep_T(const float* __restrict__ embed, const float* __restrict__ t_emb,
                         const float* __restrict__ Win_s, const int* __restrict__ tptr,
                         float* __restrict__ T, float* __restrict__ bias) {
  int f = threadIdx.x;
  int tv = tptr[0];
  double b = 0.0;
  for (int k = 0; k < 32; ++k)
    b = fma((double)t_emb[tv * 32 + k], (double)Win_s[(32 + k) * 64 + f], b);
  bias[f] = (float)b;
  for (int a = 0; a < 16; ++a) {
    double acc = 0.0;
    for (int k = 0; k < 32; ++k)
      acc = fma((double)embed[a * 32 + k], (double)Win_s[k * 64 + f], acc);
    T[a * 64 + f] = (float)acc;
  }
}

// ---------------- node init: s0 and v0 ----------------
__global__ void k_init_nodes(const float* __restrict__ coords, const float* __restrict__ mean,
                             const int* __restrict__ atoms, const float* __restrict__ T,
                             const float* __restrict__ bias, const float* __restrict__ Win_v,
                             float* __restrict__ S, float* __restrict__ V) {
  int id = blockIdx.x * 256 + threadIdx.x;
  int n = id >> 6, c = id & 63;
  double x0 = (double)coords[n * 3 + 0] - (double)mean[0];
  double x1 = (double)coords[n * 3 + 1] - (double)mean[1];
  double x2 = (double)coords[n * 3 + 2] - (double)mean[2];
  int a = atoms[n];
  S[n * 64 + c] = T[a * 64 + c] + bias[c];
  double w = (double)Win_v[c];
  V[(n * 64 + c) * 3 + 0] = (float)(x0 * w);
  V[(n * 64 + c) * 3 + 1] = (float)(x1 * w);
  V[(n * 64 + c) * 3 + 2] = (float)(x2 * w);
}

// ---------------- edge geometry + degree histogram ----------------
__global__ void k_edge_geom(const float* __restrict__ coords, const int* __restrict__ src,
                            const int* __restrict__ dst, float4* __restrict__ geom,
                            int* __restrict__ count) {
  int e = blockIdx.x * 256 + threadIdx.x;
  int se = src[e], de = dst[e];
  double rx = (double)coords[de * 3 + 0] - (double)coords[se * 3 + 0];
  double ry = (double)coords[de * 3 + 1] - (double)coords[se * 3 + 1];
  double rz = (double)coords[de * 3 + 2] - (double)coords[se * 3 + 2];
  double d2 = rx * rx + ry * ry + rz * rz + 1e-12;
  double dd = sqrt(d2);
  double inv = 1.0 / dd;
  geom[e] = make_float4((float)dd, (float)(rx * inv), (float)(ry * inv), (float)(rz * inv));
  atomicAdd(&count[de], 1);
}

// ---------------- parallel exclusive scan (3 kernels) ----------------
__global__ void k_scan1(const int* __restrict__ count, int* __restrict__ rowptr,
                        int* __restrict__ bsum) {
  __shared__ int buf[256];
  int tid = threadIdx.x, idx = blockIdx.x * 256 + tid;
  int val = count[idx];
  buf[tid] = val;
  __syncthreads();
  int incl = val;
  for (int off = 1; off < 256; off <<= 1) {
    int t = (tid >= off) ? buf[tid - off] : 0;
    __syncthreads();
    incl += t;
    buf[tid] = incl;
    __syncthreads();
  }
  rowptr[idx] = incl - val;   // exclusive within block
  if (tid == 255) bsum[blockIdx.x] = incl;
}

__global__ void k_scan2(int* __restrict__ bsum, int* __restrict__ rowptr) {
  int lane = threadIdx.x;  // 64 threads
  int v = bsum[lane];
  int incl = v;
  for (int off = 1; off < 64; off <<= 1) {
    int t = __shfl_up(incl, off);
    if (lane >= off) incl += t;
  }
  bsum[lane] = incl - v;      // exclusive block offset
  if (lane == 63) rowptr[NN] = incl;
}

__global__ void k_scan3(int* __restrict__ rowptr, int* __restrict__ cursor,
                        const int* __restrict__ bsum) {
  int idx = blockIdx.x * 256 + threadIdx.x;
  int v = rowptr[idx] + bsum[blockIdx.x];
  rowptr[idx] = v;
  cursor[idx] = v;
}

// scatter edge payloads into CSR order: srcc[pos], geomc[pos]
__global__ void k_scatter(const int* __restrict__ dst, const int* __restrict__ src,
                          const float4* __restrict__ geom, int* __restrict__ cursor,
                          int* __restrict__ srcc, float4* __restrict__ geomc) {
  int e = blockIdx.x * 256 + threadIdx.x;
  int de = dst[e];
  int pos = atomicAdd(&cursor[de], 1);
  srcc[pos] = src[e];
  geomc[pos] = geom[e];
}

// ---------------- fused per-layer pre-work: rad | node_v | node_s ----------------
// rad is LDS-FREE: W1/b1 are wave-uniform (scalar loads -> SGPRs); each lane
// recomputes the 32 hid values locally (f32 hid validated end-to-end in r18:
// absmax identical). Only w2r[32] lives in VGPRs (~52 total, no spill).
// Rebalanced for cheap rad: 224 / 512 / 288.
#define RAD_B 224
#define NV_B  512
__global__ __launch_bounds__(512) void k_layer_pre(
    const float4* __restrict__ geomc,
    const float* __restrict__ R_W1, const float* __restrict__ R_b1,
    const float* __restrict__ R_W2, const float* __restrict__ R_b2,
    float* __restrict__ radc,
    const float* __restrict__ S,
    const float* __restrict__ Wq_s, const float* __restrict__ Wk_s,
    float* __restrict__ QS, float* __restrict__ KS,
    const float* __restrict__ V,
    const float* __restrict__ Wq_v, const float* __restrict__ Wk_v,
    float* __restrict__ QV, float* __restrict__ KV, int l) {
  __shared__ float smem[8192];
  int lane = threadIdx.x & 63;
  int wv = threadIdx.x >> 6;
  if (blockIdx.x < RAD_B) {
    // ---- radial MLP over CSR edges (LDS-free; W1/b1 wave-uniform scalar) ----
    float w2r[32];
#pragma unroll
    for (int r = 0; r < 32; ++r) w2r[r] = R_W2[l * 2048 + r * 64 + lane];
    double b2v = (double)R_b2[l * 64 + lane];
    const float* w1p = R_W1 + l * 32;   // wave-uniform -> s_load
    const float* b1p = R_b1 + l * 32;
    int j0 = blockIdx.x * 8 + wv;       // slots [0, 1792)
    for (int j = j0; j < NE; j += RAD_B * 8) {
      float dd = geomc[j].x;
      double r0 = b2v, r1 = 0.0, r2 = 0.0, r3 = 0.0;
#pragma unroll
      for (int r = 0; r < 32; r += 4) {
        float h0 = fmaxf(fmaf(dd, w1p[r + 0], b1p[r + 0]), 0.f);
        float h1 = fmaxf(fmaf(dd, w1p[r + 1], b1p[r + 1]), 0.f);
        float h2 = fmaxf(fmaf(dd, w1p[r + 2], b1p[r + 2]), 0.f);
        float h3 = fmaxf(fmaf(dd, w1p[r + 3], b1p[r + 3]), 0.f);
        r0 = fma((double)h0, (double)w2r[r + 0], r0);
        r1 = fma((double)h1, (double)w2r[r + 1], r1);
        r2 = fma((double)h2, (double)w2r[r + 2], r2);
        r3 = fma((double)h3, (double)w2r[r + 3], r3);
      }
      radc[((size_t)j << 6) + lane] = (float)((r0 + r1) + (r2 + r3));
    }
  } else if (blockIdx.x < RAD_B + NV_B) {
    // ---- v-part node transform (interleaved float2 weights: 1 ds_read_b64/c) ----
    float2* w2 = (float2*)smem;              // 4096 float2 = 32 KB
    for (int i = threadIdx.x; i < 4096; i += 512)
      w2[i] = make_float2(Wq_v[l * 4096 + i], Wk_v[l * 4096 + i]);
    __syncthreads();
    int slot = (blockIdx.x - RAD_B) * 8 + wv;   // [0, 4096)
    for (int n = slot; n < NN; n += NV_B * 8) {
      float v0 = V[(n * 64 + lane) * 3 + 0];
      float v1 = V[(n * 64 + lane) * 3 + 1];
      float v2 = V[(n * 64 + lane) * 3 + 2];
      double aqv0 = 0.0, aqv1 = 0.0, aqv2 = 0.0;
      double akv0 = 0.0, akv1 = 0.0, akv2 = 0.0;
#pragma unroll 8
      for (int c = 0; c < 64; ++c) {
        double u0 = (double)__shfl(v0, c);
        double u1 = (double)__shfl(v1, c);
        double u2 = (double)__shfl(v2, c);
        float2 wc = w2[c * 64 + lane];
        double wq = (double)wc.x;
        double wk = (double)wc.y;
        aqv0 = fma(u0, wq, aqv0); aqv1 = fma(u1, wq, aqv1); aqv2 = fma(u2, wq, aqv2);
        akv0 = fma(u0, wk, akv0); akv1 = fma(u1, wk, akv1); akv2 = fma(u2, wk, akv2);
      }
      QV[(n * 64 + lane) * 3 + 0] = (float)aqv0;
      QV[(n * 64 + lane) * 3 + 1] = (float)aqv1;
      QV[(n * 64 + lane) * 3 + 2] = (float)aqv2;
      KV[(n * 64 + lane) * 3 + 0] = (float)akv0;
      KV[(n * 64 + lane) * 3 + 1] = (float)akv1;
      KV[(n * 64 + lane) * 3 + 2] = (float)akv2;
    }
  } else {
    // ---- s-part node transform (float2 weights + even/odd split accumulators) ----
    float2* w2 = (float2*)smem;              // 4096 float2 = 32 KB
    for (int i = threadIdx.x; i < 4096; i += 512)
      w2[i] = make_float2(Wq_s[l * 4096 + i], Wk_s[l * 4096 + i]);
    __syncthreads();
    int slot = (blockIdx.x - RAD_B - NV_B) * 8 + wv;  // [0, 2304)
    for (int n = slot; n < NN; n += (1024 - RAD_B - NV_B) * 8) {
      float sv = S[n * 64 + lane];
      double aq0 = 0.0, ak0 = 0.0, aq1 = 0.0, ak1 = 0.0;
#pragma unroll 8
      for (int c = 0; c < 64; c += 2) {
        double s0 = (double)__shfl(sv, c);
        double s1 = (double)__shfl(sv, c + 1);
        float2 w0 = w2[c * 64 + lane];
        float2 w1 = w2[(c + 1) * 64 + lane];
        aq0 = fma(s0, (double)w0.x, aq0); ak0 = fma(s0, (double)w0.y, ak0);
        aq1 = fma(s1, (double)w1.x, aq1); ak1 = fma(s1, (double)w1.y, ak1);
      }
      QS[n * 64 + lane] = (float)(aq0 + aq1);
      KS[n * 64 + lane] = (float)(ak0 + ak1);
    }
  }
}

// ---------------- per-layer aggregation + node update ----------------
// One wave per destination node (1024 blocks x 8 waves, 2 nodes per wave,
// serial node loop — round-11 form; compiler's own schedule wins here).
// lane = h*8 + c. Online softmax; f32 storage, f64 logits/softmax/accumulation.
__global__ void k_aggregate(const float* __restrict__ QS, const float* __restrict__ KS,
                            const float* __restrict__ QV, const float* __restrict__ KV,
                            const float4* __restrict__ geomc, const float* __restrict__ radc,
                            const int* __restrict__ rowptr, const int* __restrict__ srcc,
                            const float* __restrict__ Wo_s, const float* __restrict__ Wo_v,
                            float* __restrict__ S, float* __restrict__ V, int l) {
  __shared__ float wos[4096];
  __shared__ float wov[4096];
  for (int i = threadIdx.x; i < 4096; i += 512) {
    wos[i] = Wo_s[l * 4096 + i];
    wov[i] = Wo_v[l * 4096 + i];
  }
  __syncthreads();
  int lane = threadIdx.x & 63;
  int gb = lane & 56;
  for (int n = blockIdx.x * 8 + (threadIdx.x >> 6); n < NN; n += 8192) {
    double qs = (double)QS[n * 64 + lane];
    double qv0 = (double)QV[(n * 64 + lane) * 3 + 0];
    double qv1 = (double)QV[(n * 64 + lane) * 3 + 1];
    double qv2 = (double)QV[(n * 64 + lane) * 3 + 2];
    int rb = rowptr[n], re = rowptr[n + 1];
    double m = -INFINITY, denom = 0.0;
    double as_ = 0.0, av0 = 0.0, av1 = 0.0, av2 = 0.0;
    for (int j = rb; j < re; ++j) {
      int se = srcc[j];
      float4 g = geomc[j];
      const float4* rp = (const float4*)(radc + ((size_t)j << 6) + gb);
      float4 rA = rp[0];
      float4 rB = rp[1];
      double rh0 = (double)g.y, rh1 = (double)g.z, rh2 = (double)g.w;
      double ksv = (double)KS[se * 64 + lane];
      double kv0 = (double)KV[(se * 64 + lane) * 3 + 0];
      double kv1 = (double)KV[(se * 64 + lane) * 3 + 1];
      double kv2 = (double)KV[(se * 64 + lane) * 3 + 2];
      double c0 = (double)rA.x, c1 = (double)rA.y, c2 = (double)rA.z, c3 = (double)rA.w;
      double c4 = (double)rB.x, c5 = (double)rB.y, c6 = (double)rB.z, c7 = (double)rB.w;
      double vdr = kv0 * rh0 + kv1 * rh1 + kv2 * rh2;
      double keys = c0 * ksv + c1 * vdr;
      double vals = c4 * ksv + c5 * vdr;
      double kx = c3 * ksv;
      double vx = c7 * ksv;
      double keyv0 = fma(c2, kv0, kx * rh0);
      double keyv1 = fma(c2, kv1, kx * rh1);
      double keyv2 = fma(c2, kv2, kx * rh2);
      double valv0 = fma(c6, kv0, vx * rh0);
      double valv1 = fma(c6, kv1, vx * rh1);
      double valv2 = fma(c6, kv2, vx * rh2);
      double lg = qs * keys + qv0 * keyv0 + qv1 * keyv1 + qv2 * keyv2;
      lg += __shfl_xor(lg, 1);
      lg += __shfl_xor(lg, 2);
      lg += __shfl_xor(lg, 4);
      lg *= 0.35355339059327376220;  // 1/sqrt(8)
      double nm = fmax(m, lg);
      double sc = fast_exp(m - nm);  // first edge: tiny finite, multiplies zeros
      double a = fast_exp(lg - nm);
      m = nm;
      denom = fma(denom, sc, a);
      as_ = fma(as_, sc, a * vals);
      av0 = fma(av0, sc, a * valv0);
      av1 = fma(av1, sc, a * valv1);
      av2 = fma(av2, sc, a * valv2);
    }
    double inv = 1.0 / (denom + 1e-9);
    float aggs = (float)(as_ * inv);
    float agv0 = (float)(av0 * inv), agv1 = (float)(av1 * inv), agv2 = (float)(av2 * inv);
    double os = 0.0, ov0 = 0.0, ov1 = 0.0, ov2 = 0.0;
#pragma unroll 8
    for (int c = 0; c < 64; ++c) {
      double asc = (double)__shfl(aggs, c);
      double b0 = (double)__shfl(agv0, c);
      double b1 = (double)__shfl(agv1, c);
      double b2 = (double)__shfl(agv2, c);
      os = fma(asc, (double)wos[c * 64 + lane], os);
      double w = (double)wov[c * 64 + lane];
      ov0 = fma(b0, w, ov0); ov1 = fma(b1, w, ov1); ov2 = fma(b2, w, ov2);
    }
    double sn = (double)S[n * 64 + lane] + os;
    sn = sn * sigmoidd_(sn);
    S[n * 64 + lane] = (float)sn;
    double vr0 = (double)V[(n * 64 + lane) * 3 + 0] + ov0;
    double vr1 = (double)V[(n * 64 + lane) * 3 + 1] + ov1;
    double vr2 = (double)V[(n * 64 + lane) * 3 + 2] + ov2;
    double nrm = vr0 * vr0 + vr1 * vr1 + vr2 * vr2;
    double sg = sigmoidd_(nrm);
    V[(n * 64 + lane) * 3 + 0] = (float)(vr0 * sg);
    V[(n * 64 + lane) * 3 + 1] = (float)(vr1 * sg);
    V[(n * 64 + lane) * 3 + 2] = (float)(vr2 * sg);
  }
}

// ---------------- output projection ----------------
__global__ void k_output(const float* __restrict__ V, const float* __restrict__ Wout,
                         float* __restrict__ out) {
  int lane = threadIdx.x & 63;
  int n = blockIdx.x * 4 + (threadIdx.x >> 6);
  double w = (double)Wout[lane];
  double p0 = (double)V[(n * 64 + lane) * 3 + 0] * w;
  double p1 = (double)V[(n * 64 + lane) * 3 + 1] * w;
  double p2 = (double)V[(n * 64 + lane) * 3 + 2] * w;
  for (int off = 32; off > 0; off >>= 1) {
    p0 += __shfl_xor(p0, off);
    p1 += __shfl_xor(p1, off);
    p2 += __shfl_xor(p2, off);
  }
  if (lane == 0) {
    out[n * 3 + 0] = (float)p0;
    out[n * 3 + 1] = (float)p1;
    out[n * 3 + 2] = (float)p2;
  }
}

extern "C" void kernel_launch(void* const* d_in, const int* in_sizes, int n_in,
                              void* d_out, int out_size, void* d_ws, size_t ws_size,
                              hipStream_t stream) {
  (void)in_sizes; (void)n_in; (void)out_size; (void)ws_size;
  const float* coords = (const float*)d_in[0];
  const float* embed  = (const float*)d_in[1];
  const float* t_emb  = (const float*)d_in[2];
  const float* Win_s  = (const float*)d_in[3];
  const float* Win_v  = (const float*)d_in[4];
  const float* Wq_s   = (const float*)d_in[5];
  const float* Wq_v   = (const float*)d_in[6];
  const float* Wk_s   = (const float*)d_in[7];
  const float* Wk_v   = (const float*)d_in[8];
  const float* R_W1   = (const float*)d_in[9];
  const float* R_b1   = (const float*)d_in[10];
  const float* R_W2   = (const float*)d_in[11];
  const float* R_b2   = (const float*)d_in[12];
  const float* Wo_s   = (const float*)d_in[13];
  const float* Wo_v   = (const float*)d_in[14];
  const float* Wout_v = (const float*)d_in[15];
  const int* atoms = (const int*)d_in[16];
  const int* src   = (const int*)d_in[17];
  const int* dst   = (const int*)d_in[18];
  const int* tptr  = (const int*)d_in[19];

  float* ws    = (float*)d_ws;
  float* part  = ws + OFF_PART;
  float* mean  = ws + OFF_MEAN;
  float* Tp    = ws + OFF_T;
  float* bias  = ws + OFF_BIAS;
  float* Sp    = ws + OFF_S;
  float* Vp    = ws + OFF_V;
  float4* geom  = (float4*)(ws + OFF_GEOM);
  float4* geomc = (float4*)(ws + OFF_GEOMC);
  float* QSp   = ws + OFF_QS;
  float* KSp   = ws + OFF_KS;
  float* QVp   = ws + OFF_QV;
  float* KVp   = ws + OFF_KV;
  float* radc  = ws + OFF_RAD;
  int* bsum   = (int*)d_ws + OFF_PART;
  int* rowptr = (int*)d_ws + I_ROWPTR;
  int* cursor = (int*)d_ws + I_CURSOR;
  int* srcc   = (int*)d_ws + I_SRCC;

  k_mean_partial<<<64, 256, 0, stream>>>(coords, part);
  k_mean_final<<<1, 64, 0, stream>>>(part, mean);
  k_prep_T<<<1, 64, 0, stream>>>(embed, t_emb, Win_s, tptr, Tp, bias);
  k_init_nodes<<<4096, 256, 0, stream>>>(coords, mean, atoms, Tp, bias, Win_v, Sp, Vp);

  hipMemsetAsync(cursor, 0, NN * sizeof(int), stream);
  k_edge_geom<<<NE / 256, 256, 0, stream>>>(coords, src, dst, geom, cursor);
  k_scan1<<<64, 256, 0, stream>>>(cursor, rowptr, bsum);
  k_scan2<<<1, 64, 0, stream>>>(bsum, rowptr);
  k_scan3<<<64, 256, 0, stream>>>(rowptr, cursor, bsum);
  k_scatter<<<NE / 256, 256, 0, stream>>>(dst, src, geom, cursor, srcc, geomc);

  for (int l = 0; l < 4; ++l) {
    k_layer_pre<<<1024, 512, 0, stream>>>(geomc, R_W1, R_b1, R_W2, R_b2, radc,
                                          Sp, Wq_s, Wk_s, QSp, KSp,
                                          Vp, Wq_v, Wk_v, QVp, KVp, l);
    k_aggregate<<<1024, 512, 0, stream>>>(QSp, KSp, QVp, KVp, geomc, radc, rowptr, srcc,
                                          Wo_s, Wo_v, Sp, Vp, l);
  }

  k_output<<<4096, 256, 0, stream>>>(Vp, Wout_v, (float*)d_out);
}

// Round 21
// 1203.076 us; speedup vs baseline: 1.0445x; 1.0445x over previous
//
#include <hip/hip_runtime.h>
#include <math.h>

#define NN 16384
#define NE 262144

// ---------------- workspace layout (units: 4 bytes) ----------------
constexpr size_t OFF_PART  = 0;                               // 192 (also scan bsum)
constexpr size_t OFF_MEAN  = 256;                             // 3
constexpr size_t OFF_T     = 512;                             // 16*64
constexpr size_t OFF_BIAS  = 1536;                            // 64
constexpr size_t OFF_S     = 2048;                            // NN*64
constexpr size_t OFF_V     = OFF_S     + (size_t)NN * 64;     // NN*192
constexpr size_t OFF_GEOM  = OFF_V     + (size_t)NN * 192;    // NE*4 (float4, edge order)
constexpr size_t OFF_GEOMC = OFF_GEOM  + (size_t)NE * 4;      // NE*4 (float4, CSR order)
constexpr size_t OFF_QS    = OFF_GEOMC + (size_t)NE * 4;      // NN*64
constexpr size_t OFF_KS    = OFF_QS    + (size_t)NN * 64;     // NN*64
constexpr size_t OFF_QV    = OFF_KS    + (size_t)NN * 64;     // NN*192
constexpr size_t OFF_KV    = OFF_QV    + (size_t)NN * 192;    // NN*192
constexpr size_t OFF_RAD   = OFF_KV    + (size_t)NN * 192;    // NE*64 (CSR order)
constexpr size_t OFF_INT   = OFF_RAD   + (size_t)NE * 64;
constexpr size_t I_ROWPTR  = OFF_INT;                         // NN+1
constexpr size_t I_CURSOR  = OFF_INT + 16640;                 // NN
constexpr size_t I_SRCC    = I_CURSOR + (size_t)NN;           // NE (CSR order)
// total ~= 31.8M * 4B ~= 127 MB

static __device__ __forceinline__ double sigmoidd_(double x) {
  return 1.0 / (1.0 + exp(-x));
}

// fast e^x for x <= 0 (softmax path). Rel err ~2e-13. fast_exp(0) == 1.0 exactly.
static __device__ __forceinline__ double fast_exp(double x) {
  x = fmax(x, -708.0);                       // also maps -inf -> tiny finite
  double y = x * 1.4426950408889634074;      // x * log2(e)
  double k = rint(y);
  double r = fma(k, -6.93147180369123816490e-01, x);
  r = fma(k, -1.90821492927058770002e-10, r);  // r = x - k*ln2, |r| <= 0.3466
  double p = 2.755731922398589e-7;             // 1/10!
  p = fma(p, r, 2.7557319223985893e-6);        // 1/9!
  p = fma(p, r, 2.48015873015873016e-5);       // 1/8!
  p = fma(p, r, 1.98412698412698413e-4);       // 1/7!
  p = fma(p, r, 1.38888888888888889e-3);       // 1/6!
  p = fma(p, r, 8.33333333333333333e-3);       // 1/5!
  p = fma(p, r, 4.16666666666666667e-2);       // 1/4!
  p = fma(p, r, 1.66666666666666667e-1);       // 1/3!
  p = fma(p, r, 0.5);
  p = fma(p, r, 1.0);
  p = fma(p, r, 1.0);
  long long ki = (long long)k;                 // k in [-1021, 0]
  double sc = __longlong_as_double((unsigned long long)(1023LL + ki) << 52);
  return p * sc;
}

// ---------------- mean of coordinates ----------------
__global__ void k_mean_partial(const float* __restrict__ coords, float* __restrict__ partials) {
  __shared__ double sm[3][256];
  int tid = threadIdx.x;
  int n = blockIdx.x * 256 + tid;
  sm[0][tid] = (double)coords[n * 3 + 0];
  sm[1][tid] = (double)coords[n * 3 + 1];
  sm[2][tid] = (double)coords[n * 3 + 2];
  __syncthreads();
  for (int off = 128; off > 0; off >>= 1) {
    if (tid < off) {
      sm[0][tid] += sm[0][tid + off];
      sm[1][tid] += sm[1][tid + off];
      sm[2][tid] += sm[2][tid + off];
    }
    __syncthreads();
  }
  if (tid == 0) {
    partials[blockIdx.x * 3 + 0] = (float)sm[0][0];
    partials[blockIdx.x * 3 + 1] = (float)sm[1][0];
    partials[blockIdx.x * 3 + 2] = (float)sm[2][0];
  }
}

__global__ void k_mean_final(const float* __restrict__ partials, float* __restrict__ mean) {
  int lane = threadIdx.x;
  double s0 = (double)partials[lane * 3 + 0];
  double s1 = (double)partials[lane * 3 + 1];
  double s2 = (double)partials[lane * 3 + 2];
  for (int off = 32; off > 0; off >>= 1) {
    s0 += __shfl_xor(s0, off);
    s1 += __shfl_xor(s1, off);
    s2 += __shfl_xor(s2, off);
  }
  if (lane == 0) {
    mean[0] = (float)(s0 * (1.0 / (double)NN));
    mean[1] = (float)(s1 * (1.0 / (double)NN));
    mean[2] = (float)(s2 * (1.0 / (double)NN));
  }
}

// ---------------- s-embedding table: T[a][f] and time bias ----------------
__global__ void k_prep_T(const float* __restrict__ embed, const float* __restrict__ t_emb,
                         const float* __restrict__ Win_s, const int* __restrict__ tptr,
                         float* __restrict__ T, float* __restrict__ bias) {
  int f = threadIdx.x;
  int tv = tptr[0];
  double b = 0.0;
  for (int k = 0; k < 32; ++k)
    b = fma((double)t_emb[tv * 32 + k], (double)Win_s[(32 + k) * 64 + f], b);
  bias[f] = (float)b;
  for (int a = 0; a < 16; ++a) {
    double acc = 0.0;
    for (int k = 0; k < 32; ++k)
      acc = fma((double)embed[a * 32 + k], (double)Win_s[k * 64 + f], acc);
    T[a * 64 + f] = (float)acc;
  }
}

// ---------------- node init: s0 and v0 ----------------
__global__ void k_init_nodes(const float* __restrict__ coords, const float* __restrict__ mean,
                             const int* __restrict__ atoms, const float* __restrict__ T,
                             const float* __restrict__ bias, const float* __restrict__ Win_v,
                             float* __restrict__ S, float* __restrict__ V) {
  int id = blockIdx.x * 256 + threadIdx.x;
  int n = id >> 6, c = id & 63;
  double x0 = (double)coords[n * 3 + 0] - (double)mean[0];
  double x1 = (double)coords[n * 3 + 1] - (double)mean[1];
  double x2 = (double)coords[n * 3 + 2] - (double)mean[2];
  int a = atoms[n];
  S[n * 64 + c] = T[a * 64 + c] + bias[c];
  double w = (double)Win_v[c];
  V[(n * 64 + c) * 3 + 0] = (float)(x0 * w);
  V[(n * 64 + c) * 3 + 1] = (float)(x1 * w);
  V[(n * 64 + c) * 3 + 2] = (float)(x2 * w);
}

// ---------------- edge geometry + degree histogram ----------------
__global__ void k_edge_geom(const float* __restrict__ coords, const int* __restrict__ src,
                            const int* __restrict__ dst, float4* __restrict__ geom,
                            int* __restrict__ count) {
  int e = blockIdx.x * 256 + threadIdx.x;
  int se = src[e], de = dst[e];
  double rx = (double)coords[de * 3 + 0] - (double)coords[se * 3 + 0];
  double ry = (double)coords[de * 3 + 1] - (double)coords[se * 3 + 1];
  double rz = (double)coords[de * 3 + 2] - (double)coords[se * 3 + 2];
  double d2 = rx * rx + ry * ry + rz * rz + 1e-12;
  double dd = sqrt(d2);
  double inv = 1.0 / dd;
  geom[e] = make_float4((float)dd, (float)(rx * inv), (float)(ry * inv), (float)(rz * inv));
  atomicAdd(&count[de], 1);
}

// ---------------- parallel exclusive scan (3 kernels) ----------------
__global__ void k_scan1(const int* __restrict__ count, int* __restrict__ rowptr,
                        int* __restrict__ bsum) {
  __shared__ int buf[256];
  int tid = threadIdx.x, idx = blockIdx.x * 256 + tid;
  int val = count[idx];
  buf[tid] = val;
  __syncthreads();
  int incl = val;
  for (int off = 1; off < 256; off <<= 1) {
    int t = (tid >= off) ? buf[tid - off] : 0;
    __syncthreads();
    incl += t;
    buf[tid] = incl;
    __syncthreads();
  }
  rowptr[idx] = incl - val;   // exclusive within block
  if (tid == 255) bsum[blockIdx.x] = incl;
}

__global__ void k_scan2(int* __restrict__ bsum, int* __restrict__ rowptr) {
  int lane = threadIdx.x;  // 64 threads
  int v = bsum[lane];
  int incl = v;
  for (int off = 1; off < 64; off <<= 1) {
    int t = __shfl_up(incl, off);
    if (lane >= off) incl += t;
  }
  bsum[lane] = incl - v;      // exclusive block offset
  if (lane == 63) rowptr[NN] = incl;
}

__global__ void k_scan3(int* __restrict__ rowptr, int* __restrict__ cursor,
                        const int* __restrict__ bsum) {
  int idx = blockIdx.x * 256 + threadIdx.x;
  int v = rowptr[idx] + bsum[blockIdx.x];
  rowptr[idx] = v;
  cursor[idx] = v;
}

// scatter edge payloads into CSR order: srcc[pos], geomc[pos]
__global__ void k_scatter(const int* __restrict__ dst, const int* __restrict__ src,
                          const float4* __restrict__ geom, int* __restrict__ cursor,
                          int* __restrict__ srcc, float4* __restrict__ geomc) {
  int e = blockIdx.x * 256 + threadIdx.x;
  int de = dst[e];
  int pos = atomicAdd(&cursor[de], 1);
  srcc[pos] = src[e];
  geomc[pos] = geom[e];
}

// ---------------- fused per-layer pre-work: rad | node_v | node_s ----------------
// Block-range partition; branches are wave-uniform. 32 KB LDS per block.
// Balance (issue-cost model): rad 480, node_v 368, node_s 176.
#define RAD_B 480
#define NV_B  368
__global__ __launch_bounds__(512) void k_layer_pre(
    const float4* __restrict__ geomc,
    const float* __restrict__ R_W1, const float* __restrict__ R_b1,
    const float* __restrict__ R_W2, const float* __restrict__ R_b2,
    float* __restrict__ radc,
    const float* __restrict__ S,
    const float* __restrict__ Wq_s, const float* __restrict__ Wk_s,
    float* __restrict__ QS, float* __restrict__ KS,
    const float* __restrict__ V,
    const float* __restrict__ Wq_v, const float* __restrict__ Wk_v,
    float* __restrict__ QV, float* __restrict__ KV, int l) {
  __shared__ float smem[8192];
  int lane = threadIdx.x & 63;
  int wv = threadIdx.x >> 6;
  if (blockIdx.x < RAD_B) {
    // ---- radial MLP over CSR edges (4-way split accumulator: dep chain 32->8) ----
    float* w2s = smem;                       // 2048
    float* b2s = smem + 2048;                // 64
    float2* w1b1 = (float2*)(smem + 2112);   // 32 float2
    for (int i = threadIdx.x; i < 2048; i += 512) w2s[i] = R_W2[l * 2048 + i];
    if (threadIdx.x < 64) b2s[threadIdx.x] = R_b2[l * 64 + threadIdx.x];
    if (threadIdx.x < 32)
      w1b1[threadIdx.x] = make_float2(R_W1[l * 32 + threadIdx.x], R_b1[l * 32 + threadIdx.x]);
    __syncthreads();
    double w2d[32];
#pragma unroll
    for (int r = 0; r < 32; ++r) w2d[r] = (double)w2s[r * 64 + lane];
    double b2v = (double)b2s[lane];
    float2 hwb = w1b1[lane & 31];
    int j0 = blockIdx.x * 8 + wv;            // slots [0, 3840)
    for (int j = j0; j < NE; j += RAD_B * 8) {
      float dd = geomc[j].x;
      double hd = fma((double)dd, (double)hwb.x, (double)hwb.y);
      float hidf = (float)fmax(hd, 0.0);
      double r0 = b2v, r1 = 0.0, r2 = 0.0, r3 = 0.0;
#pragma unroll
      for (int r = 0; r < 32; r += 4) {
        r0 = fma((double)__shfl(hidf, r + 0), w2d[r + 0], r0);
        r1 = fma((double)__shfl(hidf, r + 1), w2d[r + 1], r1);
        r2 = fma((double)__shfl(hidf, r + 2), w2d[r + 2], r2);
        r3 = fma((double)__shfl(hidf, r + 3), w2d[r + 3], r3);
      }
      radc[((size_t)j << 6) + lane] = (float)((r0 + r1) + (r2 + r3));
    }
  } else if (blockIdx.x < RAD_B + NV_B) {
    // ---- v-part node transform (interleaved float2 weights: 1 ds_read_b64/c) ----
    float2* w2 = (float2*)smem;              // 4096 float2 = 32 KB
    for (int i = threadIdx.x; i < 4096; i += 512)
      w2[i] = make_float2(Wq_v[l * 4096 + i], Wk_v[l * 4096 + i]);
    __syncthreads();
    int slot = (blockIdx.x - RAD_B) * 8 + wv;   // [0, 2944)
    for (int n = slot; n < NN; n += NV_B * 8) {
      float v0 = V[(n * 64 + lane) * 3 + 0];
      float v1 = V[(n * 64 + lane) * 3 + 1];
      float v2 = V[(n * 64 + lane) * 3 + 2];
      double aqv0 = 0.0, aqv1 = 0.0, aqv2 = 0.0;
      double akv0 = 0.0, akv1 = 0.0, akv2 = 0.0;
#pragma unroll 8
      for (int c = 0; c < 64; ++c) {
        double u0 = (double)__shfl(v0, c);
        double u1 = (double)__shfl(v1, c);
        double u2 = (double)__shfl(v2, c);
        float2 wc = w2[c * 64 + lane];
        double wq = (double)wc.x;
        double wk = (double)wc.y;
        aqv0 = fma(u0, wq, aqv0); aqv1 = fma(u1, wq, aqv1); aqv2 = fma(u2, wq, aqv2);
        akv0 = fma(u0, wk, akv0); akv1 = fma(u1, wk, akv1); akv2 = fma(u2, wk, akv2);
      }
      QV[(n * 64 + lane) * 3 + 0] = (float)aqv0;
      QV[(n * 64 + lane) * 3 + 1] = (float)aqv1;
      QV[(n * 64 + lane) * 3 + 2] = (float)aqv2;
      KV[(n * 64 + lane) * 3 + 0] = (float)akv0;
      KV[(n * 64 + lane) * 3 + 1] = (float)akv1;
      KV[(n * 64 + lane) * 3 + 2] = (float)akv2;
    }
  } else {
    // ---- s-part node transform (float2 weights + even/odd split accumulators) ----
    float2* w2 = (float2*)smem;              // 4096 float2 = 32 KB
    for (int i = threadIdx.x; i < 4096; i += 512)
      w2[i] = make_float2(Wq_s[l * 4096 + i], Wk_s[l * 4096 + i]);
    __syncthreads();
    int slot = (blockIdx.x - RAD_B - NV_B) * 8 + wv;  // [0, 1408)
    for (int n = slot; n < NN; n += (1024 - RAD_B - NV_B) * 8) {
      float sv = S[n * 64 + lane];
      double aq0 = 0.0, ak0 = 0.0, aq1 = 0.0, ak1 = 0.0;
#pragma unroll 8
      for (int c = 0; c < 64; c += 2) {
        double s0 = (double)__shfl(sv, c);
        double s1 = (double)__shfl(sv, c + 1);
        float2 w0 = w2[c * 64 + lane];
        float2 w1 = w2[(c + 1) * 64 + lane];
        aq0 = fma(s0, (double)w0.x, aq0); ak0 = fma(s0, (double)w0.y, ak0);
        aq1 = fma(s1, (double)w1.x, aq1); ak1 = fma(s1, (double)w1.y, ak1);
      }
      QS[n * 64 + lane] = (float)(aq0 + aq1);
      KS[n * 64 + lane] = (float)(ak0 + ak1);
    }
  }
}

// ---------------- per-layer aggregation + node update ----------------
// One wave per destination node (1024 blocks x 8 waves, 2 nodes per wave,
// serial node loop — round-11 form; compiler's own schedule wins here).
// lane = h*8 + c. Online softmax; f32 storage, f64 logits/softmax/accumulation.
__global__ void k_aggregate(const float* __restrict__ QS, const float* __restrict__ KS,
                            const float* __restrict__ QV, const float* __restrict__ KV,
                            const float4* __restrict__ geomc, const float* __restrict__ radc,
                            const int* __restrict__ rowptr, const int* __restrict__ srcc,
                            const float* __restrict__ Wo_s, const float* __restrict__ Wo_v,
                            float* __restrict__ S, float* __restrict__ V, int l) {
  __shared__ float wos[4096];
  __shared__ float wov[4096];
  for (int i = threadIdx.x; i < 4096; i += 512) {
    wos[i] = Wo_s[l * 4096 + i];
    wov[i] = Wo_v[l * 4096 + i];
  }
  __syncthreads();
  int lane = threadIdx.x & 63;
  int gb = lane & 56;
  for (int n = blockIdx.x * 8 + (threadIdx.x >> 6); n < NN; n += 8192) {
    double qs = (double)QS[n * 64 + lane];
    double qv0 = (double)QV[(n * 64 + lane) * 3 + 0];
    double qv1 = (double)QV[(n * 64 + lane) * 3 + 1];
    double qv2 = (double)QV[(n * 64 + lane) * 3 + 2];
    int rb = rowptr[n], re = rowptr[n + 1];
    double m = -INFINITY, denom = 0.0;
    double as_ = 0.0, av0 = 0.0, av1 = 0.0, av2 = 0.0;
    for (int j = rb; j < re; ++j) {
      int se = srcc[j];
      float4 g = geomc[j];
      const float4* rp = (const float4*)(radc + ((size_t)j << 6) + gb);
      float4 rA = rp[0];
      float4 rB = rp[1];
      double rh0 = (double)g.y, rh1 = (double)g.z, rh2 = (double)g.w;
      double ksv = (double)KS[se * 64 + lane];
      double kv0 = (double)KV[(se * 64 + lane) * 3 + 0];
      double kv1 = (double)KV[(se * 64 + lane) * 3 + 1];
      double kv2 = (double)KV[(se * 64 + lane) * 3 + 2];
      double c0 = (double)rA.x, c1 = (double)rA.y, c2 = (double)rA.z, c3 = (double)rA.w;
      double c4 = (double)rB.x, c5 = (double)rB.y, c6 = (double)rB.z, c7 = (double)rB.w;
      double vdr = kv0 * rh0 + kv1 * rh1 + kv2 * rh2;
      double keys = c0 * ksv + c1 * vdr;
      double vals = c4 * ksv + c5 * vdr;
      double kx = c3 * ksv;
      double vx = c7 * ksv;
      double keyv0 = fma(c2, kv0, kx * rh0);
      double keyv1 = fma(c2, kv1, kx * rh1);
      double keyv2 = fma(c2, kv2, kx * rh2);
      double valv0 = fma(c6, kv0, vx * rh0);
      double valv1 = fma(c6, kv1, vx * rh1);
      double valv2 = fma(c6, kv2, vx * rh2);
      double lg = qs * keys + qv0 * keyv0 + qv1 * keyv1 + qv2 * keyv2;
      lg += __shfl_xor(lg, 1);
      lg += __shfl_xor(lg, 2);
      lg += __shfl_xor(lg, 4);
      lg *= 0.35355339059327376220;  // 1/sqrt(8)
      double nm = fmax(m, lg);
      double sc = fast_exp(m - nm);  // first edge: tiny finite, multiplies zeros
      double a = fast_exp(lg - nm);
      m = nm;
      denom = fma(denom, sc, a);
      as_ = fma(as_, sc, a * vals);
      av0 = fma(av0, sc, a * valv0);
      av1 = fma(av1, sc, a * valv1);
      av2 = fma(av2, sc, a * valv2);
    }
    double inv = 1.0 / (denom + 1e-9);
    float aggs = (float)(as_ * inv);
    float agv0 = (float)(av0 * inv), agv1 = (float)(av1 * inv), agv2 = (float)(av2 * inv);
    double os = 0.0, ov0 = 0.0, ov1 = 0.0, ov2 = 0.0;
#pragma unroll 8
    for (int c = 0; c < 64; ++c) {
      double asc = (double)__shfl(aggs, c);
      double b0 = (double)__shfl(agv0, c);
      double b1 = (double)__shfl(agv1, c);
      double b2 = (double)__shfl(agv2, c);
      os = fma(asc, (double)wos[c * 64 + lane], os);
      double w = (double)wov[c * 64 + lane];
      ov0 = fma(b0, w, ov0); ov1 = fma(b1, w, ov1); ov2 = fma(b2, w, ov2);
    }
    double sn = (double)S[n * 64 + lane] + os;
    sn = sn * sigmoidd_(sn);
    S[n * 64 + lane] = (float)sn;
    double vr0 = (double)V[(n * 64 + lane) * 3 + 0] + ov0;
    double vr1 = (double)V[(n * 64 + lane) * 3 + 1] + ov1;
    double vr2 = (double)V[(n * 64 + lane) * 3 + 2] + ov2;
    double nrm = vr0 * vr0 + vr1 * vr1 + vr2 * vr2;
    double sg = sigmoidd_(nrm);
    V[(n * 64 + lane) * 3 + 0] = (float)(vr0 * sg);
    V[(n * 64 + lane) * 3 + 1] = (float)(vr1 * sg);
    V[(n * 64 + lane) * 3 + 2] = (float)(vr2 * sg);
  }
}

// ---------------- output projection ----------------
__global__ void k_output(const float* __restrict__ V, const float* __restrict__ Wout,
                         float* __restrict__ out) {
  int lane = threadIdx.x & 63;
  int n = blockIdx.x * 4 + (threadIdx.x >> 6);
  double w = (double)Wout[lane];
  double p0 = (double)V[(n * 64 + lane) * 3 + 0] * w;
  double p1 = (double)V[(n * 64 + lane) * 3 + 1] * w;
  double p2 = (double)V[(n * 64 + lane) * 3 + 2] * w;
  for (int off = 32; off > 0; off >>= 1) {
    p0 += __shfl_xor(p0, off);
    p1 += __shfl_xor(p1, off);
    p2 += __shfl_xor(p2, off);
  }
  if (lane == 0) {
    out[n * 3 + 0] = (float)p0;
    out[n * 3 + 1] = (float)p1;
    out[n * 3 + 2] = (float)p2;
  }
}

extern "C" void kernel_launch(void* const* d_in, const int* in_sizes, int n_in,
                              void* d_out, int out_size, void* d_ws, size_t ws_size,
                              hipStream_t stream) {
  (void)in_sizes; (void)n_in; (void)out_size; (void)ws_size;
  const float* coords = (const float*)d_in[0];
  const float* embed  = (const float*)d_in[1];
  const float* t_emb  = (const float*)d_in[2];
  const float* Win_s  = (const float*)d_in[3];
  const float* Win_v  = (const float*)d_in[4];
  const float* Wq_s   = (const float*)d_in[5];
  const float* Wq_v   = (const float*)d_in[6];
  const float* Wk_s   = (const float*)d_in[7];
  const float* Wk_v   = (const float*)d_in[8];
  const float* R_W1   = (const float*)d_in[9];
  const float* R_b1   = (const float*)d_in[10];
  const float* R_W2   = (const float*)d_in[11];
  const float* R_b2   = (const float*)d_in[12];
  const float* Wo_s   = (const float*)d_in[13];
  const float* Wo_v   = (const float*)d_in[14];
  const float* Wout_v = (const float*)d_in[15];
  const int* atoms = (const int*)d_in[16];
  const int* src   = (const int*)d_in[17];
  const int* dst   = (const int*)d_in[18];
  const int* tptr  = (const int*)d_in[19];

  float* ws    = (float*)d_ws;
  float* part  = ws + OFF_PART;
  float* mean  = ws + OFF_MEAN;
  float* Tp    = ws + OFF_T;
  float* bias  = ws + OFF_BIAS;
  float* Sp    = ws + OFF_S;
  float* Vp    = ws + OFF_V;
  float4* geom  = (float4*)(ws + OFF_GEOM);
  float4* geomc = (float4*)(ws + OFF_GEOMC);
  float* QSp   = ws + OFF_QS;
  float* KSp   = ws + OFF_KS;
  float* QVp   = ws + OFF_QV;
  float* KVp   = ws + OFF_KV;
  float* radc  = ws + OFF_RAD;
  int* bsum   = (int*)d_ws + OFF_PART;
  int* rowptr = (int*)d_ws + I_ROWPTR;
  int* cursor = (int*)d_ws + I_CURSOR;
  int* srcc   = (int*)d_ws + I_SRCC;

  k_mean_partial<<<64, 256, 0, stream>>>(coords, part);
  k_mean_final<<<1, 64, 0, stream>>>(part, mean);
  k_prep_T<<<1, 64, 0, stream>>>(embed, t_emb, Win_s, tptr, Tp, bias);
  k_init_nodes<<<4096, 256, 0, stream>>>(coords, mean, atoms, Tp, bias, Win_v, Sp, Vp);

  hipMemsetAsync(cursor, 0, NN * sizeof(int), stream);
  k_edge_geom<<<NE / 256, 256, 0, stream>>>(coords, src, dst, geom, cursor);
  k_scan1<<<64, 256, 0, stream>>>(cursor, rowptr, bsum);
  k_scan2<<<1, 64, 0, stream>>>(bsum, rowptr);
  k_scan3<<<64, 256, 0, stream>>>(rowptr, cursor, bsum);
  k_scatter<<<NE / 256, 256, 0, stream>>>(dst, src, geom, cursor, srcc, geomc);

  for (int l = 0; l < 4; ++l) {
    k_layer_pre<<<1024, 512, 0, stream>>>(geomc, R_W1, R_b1, R_W2, R_b2, radc,
                                          Sp, Wq_s, Wk_s, QSp, KSp,
                                          Vp, Wq_v, Wk_v, QVp, KVp, l);
    k_aggregate<<<1024, 512, 0, stream>>>(QSp, KSp, QVp, KVp, geomc, radc, rowptr, srcc,
                                          Wo_s, Wo_v, Sp, Vp, l);
  }

  k_output<<<4096, 256, 0, stream>>>(Vp, Wout_v, (float*)d_out);
}